// Round 18
// baseline (266.898 us; speedup 1.0000x reference)
//
#include <hip/hip_runtime.h>
#include <cstdint>
#include <cstddef>
#include <math.h>

typedef uint16_t bf16;  // raw bf16 bits
typedef __attribute__((ext_vector_type(8))) __bf16 bf16x8;
typedef __attribute__((ext_vector_type(4))) float f32x4;
typedef __attribute__((ext_vector_type(16))) float f32x16;

#define MFMA16(a,b,c) __builtin_amdgcn_mfma_f32_16x16x32_bf16((a),(b),(c),0,0,0)
#define MFMA32(a,b,c) __builtin_amdgcn_mfma_f32_32x32x16_bf16((a),(b),(c),0,0,0)

__device__ __forceinline__ uint16_t f2bf(float f){
  uint32_t u = __float_as_uint(f);
  return (uint16_t)((u + 0x7fffu + ((u >> 16) & 1u)) >> 16);
}
__device__ __forceinline__ uint32_t pk2(float lo, float hi){
  return (uint32_t)f2bf(lo) | ((uint32_t)f2bf(hi) << 16);
}

__device__ __forceinline__ void gload_lds16(const void* g, void* l){
  __builtin_amdgcn_global_load_lds((const __attribute__((address_space(1))) void*)g,
                                   (__attribute__((address_space(3))) void*)l, 16, 0, 0);
}

// ---------------- fused prep: convert + Wq/Wk/Wv/Wo transposes + bias concat ----------------
__device__ __forceinline__ void transpose64(const float* __restrict__ in, bf16* __restrict__ out,
                                            int R, int C, int c0, int r0, float* tileRaw){
  float (*tile)[65] = reinterpret_cast<float(*)[65]>(tileRaw);
  int t = threadIdx.x;
  int fx = t & 15, fy = t >> 4;
  #pragma unroll
  for (int i = 0; i < 4; i++){
    int r = fy + i*16;
    float4 v = *reinterpret_cast<const float4*>(in + (size_t)(r0 + r)*C + c0 + fx*4);
    tile[r][fx*4+0] = v.x; tile[r][fx*4+1] = v.y;
    tile[r][fx*4+2] = v.z; tile[r][fx*4+3] = v.w;
  }
  __syncthreads();
  int gx = t & 7, gy = t >> 3;
  #pragma unroll
  for (int i = 0; i < 2; i++){
    int c = gy + i*32;
    int rr = gx*8;
    union { bf16 h[8]; uint4 u; } pk_;
    #pragma unroll
    for (int j = 0; j < 8; j++) pk_.h[j] = f2bf(tile[rr+j][c]);
    *reinterpret_cast<uint4*>(out + (size_t)(c0 + c)*R + r0 + rr) = pk_.u;
  }
}

__global__ void k_prep(const float* __restrict__ x, bf16* __restrict__ xb,
                       const float* __restrict__ Wq, bf16* __restrict__ WqT,
                       const float* __restrict__ Wk, bf16* __restrict__ WkT,
                       const float* __restrict__ Wv, bf16* __restrict__ WvT,
                       const float* __restrict__ Wo, bf16* __restrict__ WoT,
                       const float* __restrict__ bq, const float* __restrict__ bk,
                       const float* __restrict__ bv, float* __restrict__ biasAll){
  __shared__ __align__(16) float tile[64*65];
  int b = blockIdx.x;
  if (b < 8192){
    int i = (b * 256 + threadIdx.x) * 4;
    float4 v = *reinterpret_cast<const float4*>(x + i);
    uint2 pkv = make_uint2(pk2(v.x, v.y), pk2(v.z, v.w));
    *reinterpret_cast<uint2*>(xb + i) = pkv;
  } else if (b < 9216){
    int idx = b - 8192;               // Wq 2048x2048: 32x32 tiles
    transpose64(Wq, WqT, 2048, 2048, (idx & 31)*64, (idx >> 5)*64, tile);
  } else if (b < 9472){
    int idx = b - 9216;               // Wk 2048x512: 8x32 tiles
    transpose64(Wk, WkT, 2048, 512, (idx & 7)*64, (idx >> 3)*64, tile);
  } else if (b < 9728){
    int idx = b - 9472;               // Wv
    transpose64(Wv, WvT, 2048, 512, (idx & 7)*64, (idx >> 3)*64, tile);
  } else if (b < 10752){
    int idx = b - 9728;               // Wo 2048x2048
    transpose64(Wo, WoT, 2048, 2048, (idx & 31)*64, (idx >> 5)*64, tile);
  } else {
    int j = (b - 10752)*1024 + threadIdx.x*4;   // bias concat [0,3072)
    float4 v;
    if (j < 2048)      v = *reinterpret_cast<const float4*>(bq + j);
    else if (j < 2560) v = *reinterpret_cast<const float4*>(bk + j - 2048);
    else               v = *reinterpret_cast<const float4*>(bv + j - 2560);
    *reinterpret_cast<float4*>(biasAll + j) = v;
  }
}

// ---------------- 256x192 GEMM core (qkv), minimal-barrier: 1 barrier/K-tile ----------------
// 8 waves 2x4, wave C = 128x48 (acc[8][3]). BK=64, K=2048 (32 tiles).
// LDS 144KB: A TRIPLE-buffered 3x32KB @ 0/32768/65536; B dbuf 2x24KB @ 98304/122880.
__device__ __forceinline__ void gemm256x192_core(
    const bf16* __restrict__ Abase, const bf16* __restrict__ Btbase,
    char* lds, f32x4 acc[8][3])
{
  const int tid = threadIdx.x;
  const int wid = tid >> 6, lane = tid & 63;
  const int wm = wid >> 2, wn = wid & 3;
  const int lr = lane & 15, lg = lane >> 4;
  const f32x4 vzero = {0.f, 0.f, 0.f, 0.f};
  #pragma unroll
  for (int m = 0; m < 8; m++)
    #pragma unroll
    for (int n = 0; n < 3; n++)
      acc[m][n] = vzero;

  int srcA[4], srcB[3];
  #pragma unroll
  for (int i = 0; i < 4; i++){
    int db = i*8192 + tid*16;
    int row = db >> 7, sp = (db >> 4) & 7, sl = sp ^ (row & 7);
    srcA[i] = row*2048 + sl*8;
  }
  #pragma unroll
  for (int i = 0; i < 3; i++){
    int db = i*8192 + tid*16;
    int row = db >> 7, sp = (db >> 4) & 7, sl = sp ^ (row & 7);
    srcB[i] = row*2048 + sl*8;
  }
  const int dOf = wid*1024;

  int ksl[2];
  #pragma unroll
  for (int ks = 0; ks < 2; ks++) ksl[ks] = (((ks*4 + lg) ^ (lr & 7)) << 4);
  const int aB = wm*16384 + lr*128;
  const int bB = wn*6144 + lr*128;

  #define STG_A(bufOff, koff) do { \
    gload_lds16(Abase + (koff) + srcA[0], lds + (bufOff) + dOf); \
    gload_lds16(Abase + (koff) + srcA[1], lds + (bufOff) + 8192 + dOf); \
    gload_lds16(Abase + (koff) + srcA[2], lds + (bufOff) + 16384 + dOf); \
    gload_lds16(Abase + (koff) + srcA[3], lds + (bufOff) + 24576 + dOf); \
  } while(0)
  #define STG_B(bufOff, koff) do { \
    gload_lds16(Btbase + (koff) + srcB[0], lds + (bufOff) + dOf); \
    gload_lds16(Btbase + (koff) + srcB[1], lds + (bufOff) + 8192 + dOf); \
    gload_lds16(Btbase + (koff) + srcB[2], lds + (bufOff) + 16384 + dOf); \
  } while(0)

  STG_B(98304, 0);
  STG_A(0, 0);
  STG_A(32768, 64);
  asm volatile("s_waitcnt vmcnt(4)" ::: "memory");
  __builtin_amdgcn_s_barrier();

  int aOff = 0;
  int bOff = 98304;
  for (int t = 0; t < 32; t++){
    const int aStg = (aOff == 0) ? 65536 : aOff - 32768;
    const int bNxt = bOff ^ 24576;

    if (t < 31) STG_B(bNxt, (t+1)*64);
    if (t < 30) STG_A(aStg, (t+2)*64);

    bf16x8 afr[8][2], bfr[3][2];
    #pragma unroll
    for (int am = 0; am < 8; am++)
      #pragma unroll
      for (int ks = 0; ks < 2; ks++)
        afr[am][ks] = *reinterpret_cast<const bf16x8*>(lds + aOff + aB + am*2048 + ksl[ks]);
    #pragma unroll
    for (int bn = 0; bn < 3; bn++)
      #pragma unroll
      for (int ks = 0; ks < 2; ks++)
        bfr[bn][ks] = *reinterpret_cast<const bf16x8*>(lds + bOff + bB + bn*2048 + ksl[ks]);

    __builtin_amdgcn_s_setprio(1);
    #pragma unroll
    for (int am = 0; am < 8; am++)
      #pragma unroll
      for (int bn = 0; bn < 3; bn++)
        #pragma unroll
        for (int ks = 0; ks < 2; ks++)
          acc[am][bn] = MFMA16(afr[am][ks], bfr[bn][ks], acc[am][bn]);
    __builtin_amdgcn_s_setprio(0);

    if (t < 30)       asm volatile("s_waitcnt vmcnt(4)" ::: "memory");
    else if (t == 30) asm volatile("s_waitcnt vmcnt(0)" ::: "memory");
    __builtin_amdgcn_s_barrier();

    aOff = (aOff == 65536) ? 0 : aOff + 32768;
    bOff = bNxt;
  }
  #undef STG_A
  #undef STG_B
}

// ---------------- 256x128 GEMM core (oproj), minimal-barrier: 1 barrier/K-tile ----------------
__device__ __forceinline__ void gemm256x128_core(
    const bf16* __restrict__ Abase, const bf16* __restrict__ Btbase,
    char* lds, f32x4 acc[4][4])
{
  const int tid = threadIdx.x;
  const int wid = tid >> 6, lane = tid & 63;
  const int wm = wid >> 1, wn = wid & 1;
  const int lr = lane & 15, lg = lane >> 4;
  const f32x4 vzero = {0.f, 0.f, 0.f, 0.f};
  #pragma unroll
  for (int m = 0; m < 4; m++)
    #pragma unroll
    for (int n = 0; n < 4; n++)
      acc[m][n] = vzero;

  int srcA[4], srcB[2];
  #pragma unroll
  for (int i = 0; i < 4; i++){
    int db = i*8192 + tid*16;
    int row = db >> 7, sp = (db >> 4) & 7, sl = sp ^ (row & 7);
    srcA[i] = row*2048 + sl*8;
  }
  #pragma unroll
  for (int i = 0; i < 2; i++){
    int db = i*8192 + tid*16;
    int row = db >> 7, sp = (db >> 4) & 7, sl = sp ^ (row & 7);
    srcB[i] = row*2048 + sl*8;
  }
  const int dOf = wid*1024;

  int ksl[2];
  #pragma unroll
  for (int ks = 0; ks < 2; ks++) ksl[ks] = (((ks*4 + lg) ^ (lr & 7)) << 4);
  const int aB = wm*8192 + lr*128;
  const int bB = wn*8192 + lr*128;

  #define STG_A(bufOff, koff) do { \
    gload_lds16(Abase + (koff) + srcA[0], lds + (bufOff) + dOf); \
    gload_lds16(Abase + (koff) + srcA[1], lds + (bufOff) + 8192 + dOf); \
    gload_lds16(Abase + (koff) + srcA[2], lds + (bufOff) + 16384 + dOf); \
    gload_lds16(Abase + (koff) + srcA[3], lds + (bufOff) + 24576 + dOf); \
  } while(0)
  #define STG_B(bufOff, koff) do { \
    gload_lds16(Btbase + (koff) + srcB[0], lds + (bufOff) + dOf); \
    gload_lds16(Btbase + (koff) + srcB[1], lds + (bufOff) + 8192 + dOf); \
  } while(0)

  STG_B(98304, 0);
  STG_A(0, 0);
  STG_B(114688, 64);
  STG_A(32768, 64);
  asm volatile("s_waitcnt vmcnt(6)" ::: "memory");
  __builtin_amdgcn_s_barrier();

  int aOff = 0;
  int bIdx = 0;
  for (int t = 0; t < 32; t++){
    const int bOff = 98304 + bIdx*16384;
    const int aStg = (aOff == 0) ? 65536 : aOff - 32768;
    const int bStg = 98304 + ((bIdx == 0) ? 2 : bIdx - 1)*16384;

    if (t < 30){
      STG_B(bStg, (t+2)*64);
      STG_A(aStg, (t+2)*64);
    }

    bf16x8 afr[4][2], bfr[4][2];
    #pragma unroll
    for (int am = 0; am < 4; am++)
      #pragma unroll
      for (int ks = 0; ks < 2; ks++)
        afr[am][ks] = *reinterpret_cast<const bf16x8*>(lds + aOff + aB + am*2048 + ksl[ks]);
    #pragma unroll
    for (int bn = 0; bn < 4; bn++)
      #pragma unroll
      for (int ks = 0; ks < 2; ks++)
        bfr[bn][ks] = *reinterpret_cast<const bf16x8*>(lds + bOff + bB + bn*2048 + ksl[ks]);

    __builtin_amdgcn_s_setprio(1);
    #pragma unroll
    for (int am = 0; am < 4; am++)
      #pragma unroll
      for (int bn = 0; bn < 4; bn++)
        #pragma unroll
        for (int ks = 0; ks < 2; ks++)
          acc[am][bn] = MFMA16(afr[am][ks], bfr[bn][ks], acc[am][bn]);
    __builtin_amdgcn_s_setprio(0);

    if (t < 30)       asm volatile("s_waitcnt vmcnt(6)" ::: "memory");
    else if (t == 30) asm volatile("s_waitcnt vmcnt(0)" ::: "memory");
    __builtin_amdgcn_s_barrier();

    aOff = (aOff == 65536) ? 0 : aOff + 32768;
    bIdx = (bIdx == 2) ? 0 : bIdx + 1;
  }
  #undef STG_A
  #undef STG_B
}

// ---------------- fused QKV projection: concatenated N=3072, BN=192, grid (16,16)=256 blocks ----------------
__global__ __launch_bounds__(512, 1) void k_qkv(
    const bf16* __restrict__ xb, const bf16* __restrict__ WT,
    const float* __restrict__ biasAll,
    bf16* __restrict__ qo, bf16* __restrict__ ko, bf16* __restrict__ vtp)
{
  __shared__ __align__(16) char lds[147456];
  int m0 = blockIdx.x * 256;
  int y  = blockIdx.y;
  f32x4 acc[8][3];
  gemm256x192_core(xb + (size_t)m0*2048, WT + (size_t)y*192*2048, lds, acc);
  const int tid = threadIdx.x, wid = tid >> 6, lane = tid & 63;
  const int wm = wid >> 2, wn = wid & 3, lr = lane & 15, lg = lane >> 4;
  #pragma unroll
  for (int bn = 0; bn < 3; bn++){
    int fb = y*192 + wn*48 + bn*16;     // wave-uniform frag base col
    float bb = biasAll[fb + lr];
    if (fb < 2048){
      // Q (pre-scaled by 0.125*log2e)
      #pragma unroll
      for (int am = 0; am < 8; am++)
        #pragma unroll
        for (int r = 0; r < 4; r++){
          int row = m0 + wm*128 + am*16 + lg*4 + r;
          qo[(size_t)row*2048 + fb + lr] = f2bf((acc[am][bn][r] + bb) * 0.18033688011112042f);
        }
    } else if (fb < 2560){
      int c = fb - 2048 + lr;
      #pragma unroll
      for (int am = 0; am < 8; am++)
        #pragma unroll
        for (int r = 0; r < 4; r++){
          int row = m0 + wm*128 + am*16 + lg*4 + r;
          ko[(size_t)row*512 + c] = f2bf(acc[am][bn][r] + bb);
        }
    } else {
      int vcol = fb - 2560 + lr;
      #pragma unroll
      for (int am = 0; am < 8; am++){
        int row0 = m0 + wm*128 + am*16 + lg*4;
        int bi = row0 >> 11, tl = row0 & 2047;
        union { bf16 h[4]; uint2 u; } pk_;
        #pragma unroll
        for (int r = 0; r < 4; r++) pk_.h[r] = f2bf(acc[am][bn][r] + bb);
        *reinterpret_cast<uint2*>(vtp + ((size_t)bi*512 + vcol)*2048 + tl) = pk_.u;
      }
    }
  }
}

// ---------------- O projection (256x128 minimal-barrier core, fp32 out), grid (16,16) ----------------
__global__ __launch_bounds__(512, 1) void k_oproj(
    const bf16* __restrict__ ab, const bf16* __restrict__ WoT,
    const float* __restrict__ bo, float* __restrict__ outp)
{
  __shared__ __align__(16) char lds[147456];
  int m0 = blockIdx.x * 256, n0 = blockIdx.y * 128;
  f32x4 acc[4][4];
  gemm256x128_core(ab + (size_t)m0*2048, WoT + (size_t)n0*2048, lds, acc);
  const int tid = threadIdx.x, wid = tid >> 6, lane = tid & 63;
  const int wm = wid >> 1, wn = wid & 1, lr = lane & 15, lg = lane >> 4;
  #pragma unroll
  for (int bn = 0; bn < 4; bn++){
    int col = n0 + wn*64 + bn*16 + lr;
    float bb = bo[col];
    #pragma unroll
    for (int am = 0; am < 4; am++)
      #pragma unroll
      for (int r = 0; r < 4; r++){
        int row = m0 + wm*64 + am*16 + lg*4 + r;
        outp[(size_t)row*2048 + col] = acc[am][bn][r] + bb;
      }
  }
}

// ---------------- flash attention v9: LDS-free, barrier-free, L2-direct K/V ----------------
// grid (8 qtiles, 64 bh) = 512 blocks, 256 thr (4 waves x 64 q-rows, 2 groups), KVBLK=64.
// K/V per (b,kvh) = 512KB, L2-resident (16 blocks share each stream) -> MFMA operands load
// directly from global (guide common-mistake #7: don't LDS-stage L2-fit data).
// Zero barriers / zero LDS -> waves fully independent; launch_bounds(256,3) -> 3 blocks/CU
// (12 waves/CU, 1.5x TLP vs v8) to hide L2 latency by TLP instead of staging.
__global__ __launch_bounds__(256, 3) void k_flash(
    const bf16* __restrict__ q, const bf16* __restrict__ kmat,
    const bf16* __restrict__ vt, bf16* __restrict__ ao)
{
  const int tid = threadIdx.x;
  const int wid = tid >> 6, lane = tid & 63;
  const int l31 = lane & 31, hi = lane >> 5;
  const int bh = blockIdx.y;
  const int b = bh >> 5, hq = bh & 31, kvh = hq >> 2;
  const int qt = blockIdx.x;            // 0..7
  const int qrow0 = b*2048 + qt*256 + wid*64;

  // Q fragments: qf[g][t][j] = Q[q = g*32 + l31][d = 16t + 8hi + j]
  bf16x8 qf[2][4];
  #pragma unroll
  for (int g = 0; g < 2; g++){
    const bf16* qrow = q + (size_t)(qrow0 + g*32 + l31)*2048 + hq*64 + hi*8;
    #pragma unroll
    for (int t = 0; t < 4; t++)
      qf[g][t] = *reinterpret_cast<const bf16x8*>(qrow + t*16);
  }

  f32x16 oacc[2][2];
  #pragma unroll
  for (int g = 0; g < 2; g++)
    #pragma unroll
    for (int n = 0; n < 2; n++)
      #pragma unroll
      for (int r = 0; r < 16; r++) oacc[g][n][r] = 0.f;
  float rsg[2][2];
  rsg[0][0]=0.f; rsg[0][1]=0.f; rsg[1][0]=0.f; rsg[1][1]=0.f;
  const f32x16 zv = {0.f,0.f,0.f,0.f,0.f,0.f,0.f,0.f,0.f,0.f,0.f,0.f,0.f,0.f,0.f,0.f};

  // per-lane K row pointers (rows 32n + l31; col kvh*64 + hi*8), advanced 64 rows/tile
  const bf16* k0 = kmat + ((size_t)b*2048 + l31)*512 + kvh*64 + hi*8;
  const bf16* k1 = k0 + 32*512;
  // per-lane V^T row pointers (rows d = 32nd + l31; col hi*8), advanced 64 cols/tile
  const bf16* v0 = vt + ((size_t)b*512 + kvh*64 + l31)*2048 + hi*8;
  const bf16* v1 = v0 + (size_t)32*2048;

  for (int st = 0; st < 32; st++){
    // S^T = K @ Q^T over this tile's 64 k-rows; af reads feed both q-groups
    f32x16 sc[2][2];
    #pragma unroll
    for (int t = 0; t < 4; t++){
      bf16x8 af0 = *reinterpret_cast<const bf16x8*>(k0 + t*16);
      bf16x8 af1 = *reinterpret_cast<const bf16x8*>(k1 + t*16);
      if (t == 0){
        sc[0][0] = MFMA32(af0, qf[0][0], zv);
        sc[1][0] = MFMA32(af0, qf[1][0], zv);
        sc[0][1] = MFMA32(af1, qf[0][0], zv);
        sc[1][1] = MFMA32(af1, qf[1][0], zv);
      } else {
        sc[0][0] = MFMA32(af0, qf[0][t], sc[0][0]);
        sc[1][0] = MFMA32(af0, qf[1][t], sc[1][0]);
        sc[0][1] = MFMA32(af1, qf[0][t], sc[0][1]);
        sc[1][1] = MFMA32(af1, qf[1][t], sc[1][1]);
      }
    }

    // softmax per group: p = exp2(s), cvt_pk pack, permlane32 half-exchange
    uint32_t pw[2][2][8];
    #pragma unroll
    for (int g = 0; g < 2; g++){
      #pragma unroll
      for (int n = 0; n < 2; n++)
        #pragma unroll
        for (int j = 0; j < 8; j++){
          float plo = __builtin_amdgcn_exp2f(sc[g][n][2*j]);
          float phi = __builtin_amdgcn_exp2f(sc[g][n][2*j+1]);
          rsg[g][j & 1] += plo + phi;
          asm("v_cvt_pk_bf16_f32 %0, %1, %2" : "=v"(pw[g][n][j]) : "v"(plo), "v"(phi));
        }
      #pragma unroll
      for (int n = 0; n < 2; n++)
        #pragma unroll
        for (int h = 0; h < 2; h++){
          asm volatile("v_permlane32_swap_b32 %0, %1" : "+v"(pw[g][n][h*4+0]), "+v"(pw[g][n][h*4+2]));
          asm volatile("v_permlane32_swap_b32 %0, %1" : "+v"(pw[g][n][h*4+1]), "+v"(pw[g][n][h*4+3]));
        }
    }

    // PV: O += P @ V — vf reads feed both q-groups
    #pragma unroll
    for (int kk = 0; kk < 4; kk++){
      int n = kk >> 1, h = kk & 1;
      union { uint32_t w[4]; bf16x8 v; } pa0, pa1;
      #pragma unroll
      for (int w_ = 0; w_ < 4; w_++){ pa0.w[w_] = pw[0][n][h*4+w_]; pa1.w[w_] = pw[1][n][h*4+w_]; }
      {
        bf16x8 vf0 = *reinterpret_cast<const bf16x8*>(v0 + kk*16);
        bf16x8 vf1 = *reinterpret_cast<const bf16x8*>(v1 + kk*16);
        oacc[0][0] = MFMA32(pa0.v, vf0, oacc[0][0]);
        oacc[1][0] = MFMA32(pa1.v, vf0, oacc[1][0]);
        oacc[0][1] = MFMA32(pa0.v, vf1, oacc[0][1]);
        oacc[1][1] = MFMA32(pa1.v, vf1, oacc[1][1]);
      }
    }

    k0 += 64*512; k1 += 64*512;
    v0 += 64;     v1 += 64;
  }

  // finalize per group: l[q] = rs(lane q) + rs(lane q+32)
  #pragma unroll
  for (int g = 0; g < 2; g++){
    float rs = rsg[g][0] + rsg[g][1];
    float l = rs + __shfl_xor(rs, 32);
    float linv = 1.f / l;
    float lv[16];
    #pragma unroll
    for (int r = 0; r < 16; r++){
      int qi = (r & 3) + 8*(r >> 2) + 4*hi;
      lv[r] = __shfl(linv, qi);
    }
    #pragma unroll
    for (int nd = 0; nd < 2; nd++)
      #pragma unroll
      for (int r = 0; r < 16; r++){
        int qi = (r & 3) + 8*(r >> 2) + 4*hi;
        int row = qrow0 + g*32 + qi;
        ao[(size_t)row*2048 + hq*64 + nd*32 + l31] = f2bf(oacc[g][nd][r] * lv[r]);
      }
  }
}

// ---------------- host launcher ----------------
extern "C" void kernel_launch(void* const* d_in, const int* in_sizes, int n_in,
                              void* d_out, int out_size, void* d_ws, size_t ws_size,
                              hipStream_t stream)
{
  const float* x  = (const float*)d_in[0];
  const float* Wq = (const float*)d_in[1];
  const float* bq = (const float*)d_in[2];
  const float* Wk = (const float*)d_in[3];
  const float* bk = (const float*)d_in[4];
  const float* Wv = (const float*)d_in[5];
  const float* bv = (const float*)d_in[6];
  const float* Wo = (const float*)d_in[7];
  const float* bo = (const float*)d_in[8];
  float* out = (float*)d_out;

  char* ws = (char*)d_ws;
  size_t off = 0;
  auto alloc = [&](size_t bytes){ char* p = ws + off; off += (bytes + 255) & ~(size_t)255; return p; };
  bf16* xb  = (bf16*)alloc(2*2048*2048*2);   // x bf16 (reused as attnout later)
  bf16* WqT = (bf16*)alloc(2048*2048*2);     // WqT/WkT/WvT contiguous = [3072][2048]
  bf16* WkT = (bf16*)alloc(512*2048*2);
  bf16* WvT = (bf16*)alloc(512*2048*2);
  bf16* WoT = (bf16*)alloc(2048*2048*2);
  bf16* qb  = (bf16*)alloc(4096*2048*2);
  bf16* kb  = (bf16*)alloc((size_t)4096*512*2);
  bf16* vtb = (bf16*)alloc((size_t)4096*512*2);
  float* biasAll = (float*)alloc(3072*4);
  bf16* aob = xb;  // alias: x_bf16 dead after projections

  k_prep<<<10755, 256, 0, stream>>>(x, xb, Wq, WqT, Wk, WkT, Wv, WvT, Wo, WoT, bq, bk, bv, biasAll);
  k_qkv<<<dim3(16,16), 512, 0, stream>>>(xb, WqT, biasAll, qb, kb, vtb);
  k_flash<<<dim3(8,64), 256, 0, stream>>>(qb, kb, vtb, aob);
  k_oproj<<<dim3(16,16), 512, 0, stream>>>(aob, WoT, bo, out);
}

// Round 19
// 178.898 us; speedup vs baseline: 1.4919x; 1.4919x over previous
//
#include <hip/hip_runtime.h>
#include <cstdint>
#include <cstddef>
#include <math.h>

typedef uint16_t bf16;  // raw bf16 bits
typedef __attribute__((ext_vector_type(8))) __bf16 bf16x8;
typedef __attribute__((ext_vector_type(4))) float f32x4;
typedef __attribute__((ext_vector_type(16))) float f32x16;

#define MFMA16(a,b,c) __builtin_amdgcn_mfma_f32_16x16x32_bf16((a),(b),(c),0,0,0)
#define MFMA32(a,b,c) __builtin_amdgcn_mfma_f32_32x32x16_bf16((a),(b),(c),0,0,0)

__device__ __forceinline__ uint16_t f2bf(float f){
  uint32_t u = __float_as_uint(f);
  return (uint16_t)((u + 0x7fffu + ((u >> 16) & 1u)) >> 16);
}
__device__ __forceinline__ uint32_t pk2(float lo, float hi){
  return (uint32_t)f2bf(lo) | ((uint32_t)f2bf(hi) << 16);
}

__device__ __forceinline__ void gload_lds16(const void* g, void* l){
  __builtin_amdgcn_global_load_lds((const __attribute__((address_space(1))) void*)g,
                                   (__attribute__((address_space(3))) void*)l, 16, 0, 0);
}

// ---------------- fused prep: convert + Wq/Wk/Wv/Wo transposes + bias concat ----------------
__device__ __forceinline__ void transpose64(const float* __restrict__ in, bf16* __restrict__ out,
                                            int R, int C, int c0, int r0, float* tileRaw){
  float (*tile)[65] = reinterpret_cast<float(*)[65]>(tileRaw);
  int t = threadIdx.x;
  int fx = t & 15, fy = t >> 4;
  #pragma unroll
  for (int i = 0; i < 4; i++){
    int r = fy + i*16;
    float4 v = *reinterpret_cast<const float4*>(in + (size_t)(r0 + r)*C + c0 + fx*4);
    tile[r][fx*4+0] = v.x; tile[r][fx*4+1] = v.y;
    tile[r][fx*4+2] = v.z; tile[r][fx*4+3] = v.w;
  }
  __syncthreads();
  int gx = t & 7, gy = t >> 3;
  #pragma unroll
  for (int i = 0; i < 2; i++){
    int c = gy + i*32;
    int rr = gx*8;
    union { bf16 h[8]; uint4 u; } pk_;
    #pragma unroll
    for (int j = 0; j < 8; j++) pk_.h[j] = f2bf(tile[rr+j][c]);
    *reinterpret_cast<uint4*>(out + (size_t)(c0 + c)*R + r0 + rr) = pk_.u;
  }
}

__global__ void k_prep(const float* __restrict__ x, bf16* __restrict__ xb,
                       const float* __restrict__ Wq, bf16* __restrict__ WqT,
                       const float* __restrict__ Wk, bf16* __restrict__ WkT,
                       const float* __restrict__ Wv, bf16* __restrict__ WvT,
                       const float* __restrict__ Wo, bf16* __restrict__ WoT,
                       const float* __restrict__ bq, const float* __restrict__ bk,
                       const float* __restrict__ bv, float* __restrict__ biasAll){
  __shared__ __align__(16) float tile[64*65];
  int b = blockIdx.x;
  if (b < 8192){
    int i = (b * 256 + threadIdx.x) * 4;
    float4 v = *reinterpret_cast<const float4*>(x + i);
    uint2 pkv = make_uint2(pk2(v.x, v.y), pk2(v.z, v.w));
    *reinterpret_cast<uint2*>(xb + i) = pkv;
  } else if (b < 9216){
    int idx = b - 8192;               // Wq 2048x2048: 32x32 tiles
    transpose64(Wq, WqT, 2048, 2048, (idx & 31)*64, (idx >> 5)*64, tile);
  } else if (b < 9472){
    int idx = b - 9216;               // Wk 2048x512: 8x32 tiles
    transpose64(Wk, WkT, 2048, 512, (idx & 7)*64, (idx >> 3)*64, tile);
  } else if (b < 9728){
    int idx = b - 9472;               // Wv
    transpose64(Wv, WvT, 2048, 512, (idx & 7)*64, (idx >> 3)*64, tile);
  } else if (b < 10752){
    int idx = b - 9728;               // Wo 2048x2048
    transpose64(Wo, WoT, 2048, 2048, (idx & 31)*64, (idx >> 5)*64, tile);
  } else {
    int j = (b - 10752)*1024 + threadIdx.x*4;   // bias concat [0,3072)
    float4 v;
    if (j < 2048)      v = *reinterpret_cast<const float4*>(bq + j);
    else if (j < 2560) v = *reinterpret_cast<const float4*>(bk + j - 2048);
    else               v = *reinterpret_cast<const float4*>(bv + j - 2560);
    *reinterpret_cast<float4*>(biasAll + j) = v;
  }
}

// ---------------- 256x192 GEMM core (qkv), minimal-barrier: 1 barrier/K-tile ----------------
// 8 waves 2x4, wave C = 128x48 (acc[8][3]). BK=64, K=2048 (32 tiles).
// LDS 144KB: A TRIPLE-buffered 3x32KB @ 0/32768/65536; B dbuf 2x24KB @ 98304/122880.
// Per tile: {stage B(t+1), A(t+2) at top; read all 22 frags; 48 MFMA (compiler-interleaved);
// vmcnt(4); barrier}. Staged buffers were last read in tile t-1 -> single tile-end barrier
// orders read-before-overwrite. vmcnt(4) leaves only A(t+2) in flight (T4).
__device__ __forceinline__ void gemm256x192_core(
    const bf16* __restrict__ Abase, const bf16* __restrict__ Btbase,
    char* lds, f32x4 acc[8][3])
{
  const int tid = threadIdx.x;
  const int wid = tid >> 6, lane = tid & 63;
  const int wm = wid >> 2, wn = wid & 3;
  const int lr = lane & 15, lg = lane >> 4;
  const f32x4 vzero = {0.f, 0.f, 0.f, 0.f};
  #pragma unroll
  for (int m = 0; m < 8; m++)
    #pragma unroll
    for (int n = 0; n < 3; n++)
      acc[m][n] = vzero;

  int srcA[4], srcB[3];
  #pragma unroll
  for (int i = 0; i < 4; i++){
    int db = i*8192 + tid*16;
    int row = db >> 7, sp = (db >> 4) & 7, sl = sp ^ (row & 7);
    srcA[i] = row*2048 + sl*8;
  }
  #pragma unroll
  for (int i = 0; i < 3; i++){
    int db = i*8192 + tid*16;
    int row = db >> 7, sp = (db >> 4) & 7, sl = sp ^ (row & 7);
    srcB[i] = row*2048 + sl*8;
  }
  const int dOf = wid*1024;

  int ksl[2];
  #pragma unroll
  for (int ks = 0; ks < 2; ks++) ksl[ks] = (((ks*4 + lg) ^ (lr & 7)) << 4);
  const int aB = wm*16384 + lr*128;          // rows wm*128 + am*16 + lr
  const int bB = wn*6144 + lr*128;           // rows wn*48 + bn*16 + lr (relative to B buf)

  #define STG_A(bufOff, koff) do { \
    gload_lds16(Abase + (koff) + srcA[0], lds + (bufOff) + dOf); \
    gload_lds16(Abase + (koff) + srcA[1], lds + (bufOff) + 8192 + dOf); \
    gload_lds16(Abase + (koff) + srcA[2], lds + (bufOff) + 16384 + dOf); \
    gload_lds16(Abase + (koff) + srcA[3], lds + (bufOff) + 24576 + dOf); \
  } while(0)
  #define STG_B(bufOff, koff) do { \
    gload_lds16(Btbase + (koff) + srcB[0], lds + (bufOff) + dOf); \
    gload_lds16(Btbase + (koff) + srcB[1], lds + (bufOff) + 8192 + dOf); \
    gload_lds16(Btbase + (koff) + srcB[2], lds + (bufOff) + 16384 + dOf); \
  } while(0)

  // prologue: B(0), A(0), A(1); vmcnt(4) retires B(0)+A(0), leaves A(1) in flight
  STG_B(98304, 0);
  STG_A(0, 0);
  STG_A(32768, 64);
  asm volatile("s_waitcnt vmcnt(4)" ::: "memory");
  __builtin_amdgcn_s_barrier();

  int aOff = 0;
  int bOff = 98304;
  for (int t = 0; t < 32; t++){
    const int aStg = (aOff == 0) ? 65536 : aOff - 32768;   // buffer of tile t+2
    const int bNxt = bOff ^ 24576;                          // other B buffer

    // stage ahead (targets were last read in tile t-1)
    if (t < 31) STG_B(bNxt, (t+1)*64);
    if (t < 30) STG_A(aStg, (t+2)*64);

    // read all fragments of tile t; compiler interleaves with MFMAs
    bf16x8 afr[8][2], bfr[3][2];
    #pragma unroll
    for (int am = 0; am < 8; am++)
      #pragma unroll
      for (int ks = 0; ks < 2; ks++)
        afr[am][ks] = *reinterpret_cast<const bf16x8*>(lds + aOff + aB + am*2048 + ksl[ks]);
    #pragma unroll
    for (int bn = 0; bn < 3; bn++)
      #pragma unroll
      for (int ks = 0; ks < 2; ks++)
        bfr[bn][ks] = *reinterpret_cast<const bf16x8*>(lds + bOff + bB + bn*2048 + ksl[ks]);

    __builtin_amdgcn_s_setprio(1);
    #pragma unroll
    for (int am = 0; am < 8; am++)
      #pragma unroll
      for (int bn = 0; bn < 3; bn++)
        #pragma unroll
        for (int ks = 0; ks < 2; ks++)
          acc[am][bn] = MFMA16(afr[am][ks], bfr[bn][ks], acc[am][bn]);
    __builtin_amdgcn_s_setprio(0);

    if (t < 30)       asm volatile("s_waitcnt vmcnt(4)" ::: "memory");
    else if (t == 30) asm volatile("s_waitcnt vmcnt(0)" ::: "memory");
    __builtin_amdgcn_s_barrier();

    aOff = (aOff == 65536) ? 0 : aOff + 32768;
    bOff = bNxt;
  }
  #undef STG_A
  #undef STG_B
}

// ---------------- 256x128 GEMM core (oproj), minimal-barrier: 1 barrier/K-tile ----------------
// 4x2 waves, wave C = 64x64 (acc[4][4]). LDS 144KB: A 3x32KB @ 0/32768/65536;
// B 3x16KB @ 98304/114688/131072. Stage B(t+2)+A(t+2) at tile top.
// vmcnt(6) at tile end certifies tile t+1 (leaves t+2's 6 in flight).
__device__ __forceinline__ void gemm256x128_core(
    const bf16* __restrict__ Abase, const bf16* __restrict__ Btbase,
    char* lds, f32x4 acc[4][4])
{
  const int tid = threadIdx.x;
  const int wid = tid >> 6, lane = tid & 63;
  const int wm = wid >> 1, wn = wid & 1;
  const int lr = lane & 15, lg = lane >> 4;
  const f32x4 vzero = {0.f, 0.f, 0.f, 0.f};
  #pragma unroll
  for (int m = 0; m < 4; m++)
    #pragma unroll
    for (int n = 0; n < 4; n++)
      acc[m][n] = vzero;

  int srcA[4], srcB[2];
  #pragma unroll
  for (int i = 0; i < 4; i++){
    int db = i*8192 + tid*16;
    int row = db >> 7, sp = (db >> 4) & 7, sl = sp ^ (row & 7);
    srcA[i] = row*2048 + sl*8;
  }
  #pragma unroll
  for (int i = 0; i < 2; i++){
    int db = i*8192 + tid*16;
    int row = db >> 7, sp = (db >> 4) & 7, sl = sp ^ (row & 7);
    srcB[i] = row*2048 + sl*8;
  }
  const int dOf = wid*1024;

  int ksl[2];
  #pragma unroll
  for (int ks = 0; ks < 2; ks++) ksl[ks] = (((ks*4 + lg) ^ (lr & 7)) << 4);
  const int aB = wm*8192 + lr*128;           // rows wm*64 + am*16 + lr
  const int bB = wn*8192 + lr*128;           // rows wn*64 + bn*16 + lr

  #define STG_A(bufOff, koff) do { \
    gload_lds16(Abase + (koff) + srcA[0], lds + (bufOff) + dOf); \
    gload_lds16(Abase + (koff) + srcA[1], lds + (bufOff) + 8192 + dOf); \
    gload_lds16(Abase + (koff) + srcA[2], lds + (bufOff) + 16384 + dOf); \
    gload_lds16(Abase + (koff) + srcA[3], lds + (bufOff) + 24576 + dOf); \
  } while(0)
  #define STG_B(bufOff, koff) do { \
    gload_lds16(Btbase + (koff) + srcB[0], lds + (bufOff) + dOf); \
    gload_lds16(Btbase + (koff) + srcB[1], lds + (bufOff) + 8192 + dOf); \
  } while(0)

  STG_B(98304, 0);
  STG_A(0, 0);
  STG_B(114688, 64);
  STG_A(32768, 64);
  asm volatile("s_waitcnt vmcnt(6)" ::: "memory");
  __builtin_amdgcn_s_barrier();

  int aOff = 0;
  int bIdx = 0;
  for (int t = 0; t < 32; t++){
    const int bOff = 98304 + bIdx*16384;
    const int aStg = (aOff == 0) ? 65536 : aOff - 32768;             // (t+2)%3
    const int bStg = 98304 + ((bIdx == 0) ? 2 : bIdx - 1)*16384;     // (t+2)%3

    if (t < 30){
      STG_B(bStg, (t+2)*64);
      STG_A(aStg, (t+2)*64);
    }

    bf16x8 afr[4][2], bfr[4][2];
    #pragma unroll
    for (int am = 0; am < 4; am++)
      #pragma unroll
      for (int ks = 0; ks < 2; ks++)
        afr[am][ks] = *reinterpret_cast<const bf16x8*>(lds + aOff + aB + am*2048 + ksl[ks]);
    #pragma unroll
    for (int bn = 0; bn < 4; bn++)
      #pragma unroll
      for (int ks = 0; ks < 2; ks++)
        bfr[bn][ks] = *reinterpret_cast<const bf16x8*>(lds + bOff + bB + bn*2048 + ksl[ks]);

    __builtin_amdgcn_s_setprio(1);
    #pragma unroll
    for (int am = 0; am < 4; am++)
      #pragma unroll
      for (int bn = 0; bn < 4; bn++)
        #pragma unroll
        for (int ks = 0; ks < 2; ks++)
          acc[am][bn] = MFMA16(afr[am][ks], bfr[bn][ks], acc[am][bn]);
    __builtin_amdgcn_s_setprio(0);

    if (t < 30)       asm volatile("s_waitcnt vmcnt(6)" ::: "memory");
    else if (t == 30) asm volatile("s_waitcnt vmcnt(0)" ::: "memory");
    __builtin_amdgcn_s_barrier();

    aOff = (aOff == 65536) ? 0 : aOff + 32768;
    bIdx = (bIdx == 2) ? 0 : bIdx + 1;
  }
  #undef STG_A
  #undef STG_B
}

// ---------------- fused QKV projection: concatenated N=3072, BN=192, grid (16,16)=256 blocks ----------------
// WT = [WqT; WkT; WvT] contiguous [3072][2048]; biasAll[3072]. Col boundaries 2048/2560 are
// multiples of 16 -> each 16-col frag is single-mode (wave-uniform branch).
__global__ __launch_bounds__(512, 1) void k_qkv(
    const bf16* __restrict__ xb, const bf16* __restrict__ WT,
    const float* __restrict__ biasAll,
    bf16* __restrict__ qo, bf16* __restrict__ ko, bf16* __restrict__ vtp)
{
  __shared__ __align__(16) char lds[147456];
  int m0 = blockIdx.x * 256;
  int y  = blockIdx.y;
  f32x4 acc[8][3];
  gemm256x192_core(xb + (size_t)m0*2048, WT + (size_t)y*192*2048, lds, acc);
  const int tid = threadIdx.x, wid = tid >> 6, lane = tid & 63;
  const int wm = wid >> 2, wn = wid & 3, lr = lane & 15, lg = lane >> 4;
  #pragma unroll
  for (int bn = 0; bn < 3; bn++){
    int fb = y*192 + wn*48 + bn*16;     // wave-uniform frag base col
    float bb = biasAll[fb + lr];
    if (fb < 2048){
      // Q (pre-scaled by 0.125*log2e)
      #pragma unroll
      for (int am = 0; am < 8; am++)
        #pragma unroll
        for (int r = 0; r < 4; r++){
          int row = m0 + wm*128 + am*16 + lg*4 + r;
          qo[(size_t)row*2048 + fb + lr] = f2bf((acc[am][bn][r] + bb) * 0.18033688011112042f);
        }
    } else if (fb < 2560){
      int c = fb - 2048 + lr;
      #pragma unroll
      for (int am = 0; am < 8; am++)
        #pragma unroll
        for (int r = 0; r < 4; r++){
          int row = m0 + wm*128 + am*16 + lg*4 + r;
          ko[(size_t)row*512 + c] = f2bf(acc[am][bn][r] + bb);
        }
    } else {
      int vcol = fb - 2560 + lr;
      #pragma unroll
      for (int am = 0; am < 8; am++){
        int row0 = m0 + wm*128 + am*16 + lg*4;
        int bi = row0 >> 11, tl = row0 & 2047;
        union { bf16 h[4]; uint2 u; } pk_;
        #pragma unroll
        for (int r = 0; r < 4; r++) pk_.h[r] = f2bf(acc[am][bn][r] + bb);
        *reinterpret_cast<uint2*>(vtp + ((size_t)bi*512 + vcol)*2048 + tl) = pk_.u;
      }
    }
  }
}

// ---------------- O projection (256x128 minimal-barrier core, fp32 out), grid (16,16) ----------------
__global__ __launch_bounds__(512, 1) void k_oproj(
    const bf16* __restrict__ ab, const bf16* __restrict__ WoT,
    const float* __restrict__ bo, float* __restrict__ outp)
{
  __shared__ __align__(16) char lds[147456];
  int m0 = blockIdx.x * 256, n0 = blockIdx.y * 128;
  f32x4 acc[4][4];
  gemm256x128_core(ab + (size_t)m0*2048, WoT + (size_t)n0*2048, lds, acc);
  const int tid = threadIdx.x, wid = tid >> 6, lane = tid & 63;
  const int wm = wid >> 1, wn = wid & 1, lr = lane & 15, lg = lane >> 4;
  #pragma unroll
  for (int bn = 0; bn < 4; bn++){
    int col = n0 + wn*64 + bn*16 + lr;
    float bb = bo[col];
    #pragma unroll
    for (int am = 0; am < 4; am++)
      #pragma unroll
      for (int r = 0; r < 4; r++){
        int row = m0 + wm*64 + am*16 + lg*4 + r;
        outp[(size_t)row*2048 + col] = acc[am][bn][r] + bb;
      }
  }
}

// ---------------- flash attention v8: counted vmcnt + raw barrier, 3-buffer LDS ----------------
// grid (4 qtiles, 64 bh) = 256 blocks = 1/CU. 8 waves x 64 q-rows (2 groups), QBLK=512, KVBLK=128.
__global__ __launch_bounds__(512, 2) void k_flash(
    const bf16* __restrict__ q, const bf16* __restrict__ kmat,
    const bf16* __restrict__ vt, bf16* __restrict__ ao)
{
  __shared__ __align__(16) char lds[98304];
  const int tid = threadIdx.x;
  const int wid = tid >> 6, lane = tid & 63;
  const int l31 = lane & 31, hi = lane >> 5;
  const int bh = blockIdx.y;
  const int b = bh >> 5, hq = bh & 31, kvh = hq >> 2;
  const int qt = blockIdx.x;
  const int qrow0 = b*2048 + qt*512 + wid*64;

  bf16x8 qf[2][4];
  #pragma unroll
  for (int g = 0; g < 2; g++){
    const bf16* qrow = q + (size_t)(qrow0 + g*32 + l31)*2048 + hq*64 + hi*8;
    #pragma unroll
    for (int t = 0; t < 4; t++)
      qf[g][t] = *reinterpret_cast<const bf16x8*>(qrow + t*16);
  }

  f32x16 oacc[2][2];
  #pragma unroll
  for (int g = 0; g < 2; g++)
    #pragma unroll
    for (int n = 0; n < 2; n++)
      #pragma unroll
      for (int r = 0; r < 16; r++) oacc[g][n][r] = 0.f;
  float rsg[2][2];
  rsg[0][0]=0.f; rsg[0][1]=0.f; rsg[1][0]=0.f; rsg[1][1]=0.f;
  const f32x16 zv = {0.f,0.f,0.f,0.f,0.f,0.f,0.f,0.f,0.f,0.f,0.f,0.f,0.f,0.f,0.f,0.f};

  const int r7 = l31 & 7;
  int A[4];
  #pragma unroll
  for (int j = 0; j < 4; j++)
    A[j] = l31*128 + (((2*j + hi) ^ r7) << 4);

  const bf16* kbase = kmat + (size_t)b*2048*512 + kvh*64;
  const bf16* vbase = vt + ((size_t)b*512 + kvh*64)*2048;

  int kSrc[2], vSrc[2];
  const int dOf = wid*1024;
  #pragma unroll
  for (int i = 0; i < 2; i++){
    int kdb = i*8192 + tid*16;
    int krow = kdb >> 7, ksp = (kdb >> 4) & 7, ksl = ksp ^ (krow & 7);
    kSrc[i] = krow*512 + ksl*8;
    int o = tid*16;
    int vrow = o >> 7, vsp = (o >> 4) & 7, vsl = vsp ^ (vrow & 7);
    vSrc[i] = vrow*2048 + i*64 + vsl*8;
  }

  #define STAGE(bo, st_) do { \
    const bf16* kb_ = kbase + (size_t)(st_)*128*512; \
    const bf16* vb_ = vbase + (st_)*128; \
    gload_lds16(kb_ + kSrc[0], lds + (bo) + dOf); \
    gload_lds16(kb_ + kSrc[1], lds + (bo) + 8192 + dOf); \
    gload_lds16(vb_ + vSrc[0], lds + 49152 + (bo) + dOf); \
    gload_lds16(vb_ + vSrc[1], lds + 49152 + (bo) + 8192 + dOf); \
  } while(0)

  #define LDK(j, imm) (*reinterpret_cast<const bf16x8*>(lds + kOff + A[j] + (imm)))
  #define LDV(j, imm) (*reinterpret_cast<const bf16x8*>(lds + 49152 + kOff + A[j] + (imm)))

  STAGE(0, 0);
  STAGE(16384, 1);

  int kOff = 0;
  int sOff = 32768;
  for (int st = 0; st < 16; st++){
    if (st == 15) asm volatile("s_waitcnt vmcnt(0)" ::: "memory");
    else          asm volatile("s_waitcnt vmcnt(4)" ::: "memory");
    __builtin_amdgcn_sched_barrier(0);
    __builtin_amdgcn_s_barrier();
    __builtin_amdgcn_sched_barrier(0);
    if (st < 14){
      STAGE(sOff, st+2);
      sOff = (sOff == 32768) ? 0 : sOff + 16384;
    }

    #pragma unroll
    for (int c = 0; c < 2; c++){
      f32x16 sc[2][2];
      __builtin_amdgcn_s_setprio(1);
      #pragma unroll
      for (int t = 0; t < 4; t++){
        bf16x8 af0 = LDK(t, c*8192);
        bf16x8 af1 = LDK(t, c*8192 + 4096);
        if (t == 0){
          sc[0][0] = MFMA32(af0, qf[0][0], zv);
          sc[1][0] = MFMA32(af0, qf[1][0], zv);
          sc[0][1] = MFMA32(af1, qf[0][0], zv);
          sc[1][1] = MFMA32(af1, qf[1][0], zv);
        } else {
          sc[0][0] = MFMA32(af0, qf[0][t], sc[0][0]);
          sc[1][0] = MFMA32(af0, qf[1][t], sc[1][0]);
          sc[0][1] = MFMA32(af1, qf[0][t], sc[0][1]);
          sc[1][1] = MFMA32(af1, qf[1][t], sc[1][1]);
        }
      }
      __builtin_amdgcn_s_setprio(0);

      uint32_t pw[2][2][8];
      #pragma unroll
      for (int g = 0; g < 2; g++){
        #pragma unroll
        for (int n = 0; n < 2; n++)
          #pragma unroll
          for (int j = 0; j < 8; j++){
            float plo = __builtin_amdgcn_exp2f(sc[g][n][2*j]);
            float phi = __builtin_amdgcn_exp2f(sc[g][n][2*j+1]);
            rsg[g][j & 1] += plo + phi;
            asm("v_cvt_pk_bf16_f32 %0, %1, %2" : "=v"(pw[g][n][j]) : "v"(plo), "v"(phi));
          }
        #pragma unroll
        for (int n = 0; n < 2; n++)
          #pragma unroll
          for (int h = 0; h < 2; h++){
            asm volatile("v_permlane32_swap_b32 %0, %1" : "+v"(pw[g][n][h*4+0]), "+v"(pw[g][n][h*4+2]));
            asm volatile("v_permlane32_swap_b32 %0, %1" : "+v"(pw[g][n][h*4+1]), "+v"(pw[g][n][h*4+3]));
          }
      }

      __builtin_amdgcn_s_setprio(1);
      #pragma unroll
      for (int kk = 0; kk < 4; kk++){
        int n = kk >> 1, h = kk & 1;
        union { uint32_t w[4]; bf16x8 v; } pa0, pa1;
        #pragma unroll
        for (int w_ = 0; w_ < 4; w_++){ pa0.w[w_] = pw[0][n][h*4+w_]; pa1.w[w_] = pw[1][n][h*4+w_]; }
        #pragma unroll
        for (int nd = 0; nd < 2; nd++){
          bf16x8 vf = LDV(kk, c*8192 + nd*4096);
          oacc[0][nd] = MFMA32(pa0.v, vf, oacc[0][nd]);
          oacc[1][nd] = MFMA32(pa1.v, vf, oacc[1][nd]);
        }
      }
      __builtin_amdgcn_s_setprio(0);
    }
    kOff = (kOff == 32768) ? 0 : kOff + 16384;
  }
  #undef STAGE
  #undef LDK
  #undef LDV

  #pragma unroll
  for (int g = 0; g < 2; g++){
    float rs = rsg[g][0] + rsg[g][1];
    float l = rs + __shfl_xor(rs, 32);
    float linv = 1.f / l;
    float lv[16];
    #pragma unroll
    for (int r = 0; r < 16; r++){
      int qi = (r & 3) + 8*(r >> 2) + 4*hi;
      lv[r] = __shfl(linv, qi);
    }
    #pragma unroll
    for (int nd = 0; nd < 2; nd++)
      #pragma unroll
      for (int r = 0; r < 16; r++){
        int qi = (r & 3) + 8*(r >> 2) + 4*hi;
        int row = qrow0 + g*32 + qi;
        ao[(size_t)row*2048 + hq*64 + nd*32 + l31] = f2bf(oacc[g][nd][r] * lv[r]);
      }
  }
}

// ---------------- host launcher ----------------
extern "C" void kernel_launch(void* const* d_in, const int* in_sizes, int n_in,
                              void* d_out, int out_size, void* d_ws, size_t ws_size,
                              hipStream_t stream)
{
  const float* x  = (const float*)d_in[0];
  const float* Wq = (const float*)d_in[1];
  const float* bq = (const float*)d_in[2];
  const float* Wk = (const float*)d_in[3];
  const float* bk = (const float*)d_in[4];
  const float* Wv = (const float*)d_in[5];
  const float* bv = (const float*)d_in[6];
  const float* Wo = (const float*)d_in[7];
  const float* bo = (const float*)d_in[8];
  float* out = (float*)d_out;

  char* ws = (char*)d_ws;
  size_t off = 0;
  auto alloc = [&](size_t bytes){ char* p = ws + off; off += (bytes + 255) & ~(size_t)255; return p; };
  bf16* xb  = (bf16*)alloc(2*2048*2048*2);   // x bf16 (reused as attnout later)
  bf16* WqT = (bf16*)alloc(2048*2048*2);     // WqT/WkT/WvT contiguous = [3072][2048]
  bf16* WkT = (bf16*)alloc(512*2048*2);
  bf16* WvT = (bf16*)alloc(512*2048*2);
  bf16* WoT = (bf16*)alloc(2048*2048*2);
  bf16* qb  = (bf16*)alloc(4096*2048*2);
  bf16* kb  = (bf16*)alloc((size_t)4096*512*2);
  bf16* vtb = (bf16*)alloc((size_t)4096*512*2);
  float* biasAll = (float*)alloc(3072*4);
  bf16* aob = xb;  // alias: x_bf16 dead after projections

  k_prep<<<10755, 256, 0, stream>>>(x, xb, Wq, WqT, Wk, WkT, Wv, WvT, Wo, WoT, bq, bk, bv, biasAll);
  k_qkv<<<dim3(16,16), 512, 0, stream>>>(xb, WqT, biasAll, qb, kb, vtb);
  k_flash<<<dim3(4,64), 512, 0, stream>>>(qb, kb, vtb, aob);
  k_oproj<<<dim3(16,16), 512, 0, stream>>>(aob, WoT, bo, out);
}